// Round 9
// baseline (256.691 us; speedup 1.0000x reference)
//
#include <hip/hip_runtime.h>
#include <hip/hip_cooperative_groups.h>
#include <stdint.h>

namespace cg = cooperative_groups;

typedef __attribute__((ext_vector_type(8))) short short8;
typedef __attribute__((ext_vector_type(8))) unsigned short u16x8;
typedef __attribute__((ext_vector_type(4))) float f32x4;

#define DEV __device__ __forceinline__

DEV float bf2f(unsigned short v) {
    union { unsigned int u; float f; } c;
    c.u = ((unsigned int)v) << 16;
    return c.f;
}
DEV unsigned short f2bf(float f) {
    union { float f; unsigned int u; } c;
    c.f = f;
    unsigned int x = c.u;
    x += 0x7fffu + ((x >> 16) & 1u);   // round-to-nearest-even
    return (unsigned short)(x >> 16);
}

// K layout: cols 0..1663 = 26 cat embeddings (26x64); cols 1664..1676 = raw
// cont features (rank-13 folding); cols 1677..1727 = zero.  KP = 1728 = 27*64.
#define KCAT 1664
#define KP   1728

// Phase-0 work units (each executed by a full 512-thread block):
//   u in [0,2048)        : embed+FM, 8 batch rows
//   u in [2048,3136)     : 2 transpose tiles (sub-block = tid>>8)
//   u in [3136,3162)     : 2 rank-13 fold blocks
//   u == 3162            : zero stats (3072 floats)
#define NU_EMB 2048
#define NU_TR  1088
#define NU_FLD 26
#define NU_ALL (NU_EMB + NU_TR + NU_FLD + 1)

// ---------------------------------------------------------------------------
// MEGA kernel: front | gemm1 | gemm2 | final, separated by grid.sync().
// 256 blocks x 512 threads, 1 block/CU (128 KiB LDS).
// ---------------------------------------------------------------------------
__global__ __launch_bounds__(512, 2) void mega(
    const int* __restrict__ cat, const float* __restrict__ cont,
    const float* __restrict__ bias,
    const float* __restrict__ t1c, const float* __restrict__ t2c,
    const float* __restrict__ t1x, const float* __restrict__ t2x,
    const float* __restrict__ W1,
    const float* __restrict__ g1, const float* __restrict__ be1,
    const float* __restrict__ W2,
    const float* __restrict__ g2, const float* __restrict__ be2,
    const float* __restrict__ W3, const float* __restrict__ b3,
    unsigned short* __restrict__ deep, float* __restrict__ fm,
    unsigned short* __restrict__ w1t, unsigned short* __restrict__ w2t,
    unsigned short* __restrict__ z1, unsigned short* __restrict__ z2,
    float* __restrict__ stats, float* __restrict__ out)
{
    __shared__ __align__(16) unsigned char smem[131072];
    cg::grid_group grid = cg::this_grid();
    const int tid = threadIdx.x;
    const int bid = blockIdx.x;
    const float invB = 1.f / 16384.f;

    float* sums1 = stats;
    float* sqs1  = stats + 1024;
    float* sums2 = stats + 2048;
    float* sqs2  = stats + 2560;

    // ======================= PHASE 0: front =======================
    for (int u = bid; u < NU_ALL; u += 256) {
        if (u < NU_EMB) {
            // ---- embed + FM: 8 rows ----
            unsigned short (*rowbuf)[KP] = (unsigned short (*)[KP])smem;  // 27648 B
            const int ty = tid >> 6;
            const int d = tid & 63;
            const int row = u * 8 + ty;
            const int* crow = cat + row * 26;
            const float* xrow = cont + row * 13;

            __syncthreads();   // protect smem reuse across grid-stride iters
            float s = 0.f, ss = 0.f;
            #pragma unroll
            for (int f = 0; f < 26; ++f) {
                int idx = crow[f];                                  // wave-uniform
                float e = t2c[((size_t)f * 100000 + idx) * 64 + d]; // 256B row
                s += e; ss += e * e;
                rowbuf[ty][f * 64 + d] = f2bf(e);
            }
            #pragma unroll
            for (int f = 0; f < 13; ++f) {
                float x = xrow[f];
                float e = t2x[f * 64 + d] * x;
                s += e; ss += e * e;
            }
            rowbuf[ty][KCAT + d] = (d < 13) ? f2bf(xrow[d]) : (unsigned short)0;

            float val = 0.5f * (s * s - ss);
            if (d < 26) val += t1c[(size_t)d * 100000 + crow[d]];
            if (d < 13) val += t1x[d] * xrow[d];
            #pragma unroll
            for (int off = 32; off; off >>= 1) val += __shfl_xor(val, off);
            if (d == 0) fm[row] = bias[0] + val;

            __syncthreads();
            // coalesced store: 8 rows x 1728 = 13824 elems
            const unsigned short* src = (const unsigned short*)smem;
            unsigned short* dst = deep + (size_t)(u * 8) * KP;
            #pragma unroll
            for (int it = 0; it < 4; ++it) {
                int off = it * 4096 + tid * 8;
                if (off < 8 * KP)
                    *(u16x8*)(dst + off) = *(const u16x8*)(src + off);
            }
        } else if (u < NU_EMB + NU_TR) {
            // ---- 2 transpose tiles (independent 256-thr sub-blocks) ----
            const int sub = tid >> 8;
            const int tsub = tid & 255;
            float (*tile)[33] = (float (*)[33])(smem + sub * 4352);  // 4224 B used
            int b = (u - NU_EMB) * 2 + sub;          // 0..2175
            const float* in; unsigned short* outw; int C, KO, bx, by;
            if (b < 1664) { in = W1; outw = w1t; C = 1024; KO = KP; bx = b & 31; by = b >> 5; }
            else { b -= 1664; in = W2; outw = w2t; C = 512; KO = 1024; bx = b & 15; by = b >> 4; }
            int c0 = bx * 32, r0 = by * 32;
            int tx = tsub & 31, ty2 = tsub >> 5;
            __syncthreads();   // protect smem reuse
            #pragma unroll
            for (int i = 0; i < 4; ++i)
                tile[ty2 + i * 8][tx] = in[(size_t)(r0 + ty2 + i * 8) * C + c0 + tx];
            __syncthreads();
            #pragma unroll
            for (int i = 0; i < 4; ++i)
                outw[(size_t)(c0 + ty2 + i * 8) * KO + r0 + tx] = f2bf(tile[tx][ty2 + i * 8]);
        } else if (u < NU_EMB + NU_TR + NU_FLD) {
            // ---- 2 rank-13 fold blocks (no smem) ----
            int q = (u - NU_EMB - NU_TR) * 2 + (tid >> 8);   // 0..51
            int f = q >> 2;
            int n = (q & 3) * 256 + (tid & 255);             // 0..1023
            float s = 0.f;
            #pragma unroll 8
            for (int d = 0; d < 64; ++d)
                s += W1[(size_t)(KCAT + f * 64 + d) * 1024 + n] * t2x[f * 64 + d];
            w1t[(size_t)n * KP + KCAT + f] = f2bf(s);
            if (f == 0)
                for (int j = KCAT + 13; j < KP; ++j)
                    w1t[(size_t)n * KP + j] = 0;
        } else {
            // ---- zero stats (3072 floats) ----
            #pragma unroll
            for (int i = 0; i < 6; ++i)
                stats[i * 512 + tid] = 0.f;
        }
    }

    grid.sync();

    // ======================= PHASE 1: gemm1 =======================
    // 256x256-tile 8-wave bf16 GEMM, counted-vmcnt 3-barrier pipeline,
    // LDS XOR swizzle, setprio, XCD swizzle, fused BN1 column stats.
    {
        const int K = KP, N = 1024;
        unsigned short* lds0 = (unsigned short*)smem;            // buf0: 32768 elems
        unsigned short* lds1 = (unsigned short*)(smem + 65536);  // buf1
        const int lane = tid & 63, wid = tid >> 6;
        const int wrow = wid >> 2, wcol = wid & 3;
        const int swzb = (bid & 7) * 32 + (bid >> 3);   // cpx = 256/8 = 32
        const int bm = swzb >> 2, bn = swzb & 3;        // nbn = 4
        const int NT = K >> 6;                          // 27

        const int srow = tid >> 3;
        const int skc  = (tid & 7) ^ (srow & 7);
        const unsigned short* Asrc = deep + (size_t)(bm * 256 + srow) * K + skc * 8;
        const unsigned short* Bsrc = w1t + (size_t)(bn * 256 + srow) * K + skc * 8;

        #define STAGE_A(kt, bptr)                                                     \
            _Pragma("unroll")                                                         \
            for (int i_ = 0; i_ < 4; ++i_)                                            \
                __builtin_amdgcn_global_load_lds(                                     \
                    (const __attribute__((address_space(1))) void*)(Asrc + (size_t)(i_ * 64) * K + (kt)), \
                    (__attribute__((address_space(3))) void*)((bptr) + tid * 8 + i_ * 4096), 16, 0, 0);
        #define STAGE_B(kt, bptr)                                                     \
            _Pragma("unroll")                                                         \
            for (int i_ = 0; i_ < 4; ++i_)                                            \
                __builtin_amdgcn_global_load_lds(                                     \
                    (const __attribute__((address_space(1))) void*)(Bsrc + (size_t)(i_ * 64) * K + (kt)), \
                    (__attribute__((address_space(3))) void*)((bptr) + 16384 + tid * 8 + i_ * 4096), 16, 0, 0);

        const int l15 = lane & 15, l7 = lane & 7, lhi = lane >> 4;
        const int xo0 = 8 * (lhi ^ l7);
        const int xo1 = 8 * ((lhi + 4) ^ l7);
        const int aRow = wrow * 128 + l15;
        const int bRow = wcol * 64 + l15;

        f32x4 acc[8][4];
        #pragma unroll
        for (int m = 0; m < 8; ++m)
            #pragma unroll
            for (int n = 0; n < 4; ++n) acc[m][n] = (f32x4){0.f, 0.f, 0.f, 0.f};

        STAGE_A(0, lds0); STAGE_B(0, lds0);
        STAGE_A(64, lds1); STAGE_B(64, lds1);
        asm volatile("s_waitcnt vmcnt(8)" ::: "memory");
        __builtin_amdgcn_s_barrier();

        for (int t = 0; t < NT; ++t) {
            unsigned short* base = (t & 1) ? lds1 : lds0;
            const int ktp = (t + 2) << 6;
            const bool pf = (t + 2) < NT;

            short8 a[4][2], bfr[4][2];
            // pA: read A-mh0 + all B; MFMA Q(0,*) x32
            #pragma unroll
            for (int mf = 0; mf < 4; ++mf) {
                a[mf][0] = *(const short8*)(base + (aRow + mf * 16) * 64 + xo0);
                a[mf][1] = *(const short8*)(base + (aRow + mf * 16) * 64 + xo1);
            }
            #pragma unroll
            for (int nf = 0; nf < 4; ++nf) {
                bfr[nf][0] = *(const short8*)(base + 16384 + (bRow + nf * 16) * 64 + xo0);
                bfr[nf][1] = *(const short8*)(base + 16384 + (bRow + nf * 16) * 64 + xo1);
            }
            __builtin_amdgcn_s_setprio(1);
            #pragma unroll
            for (int mf = 0; mf < 4; ++mf)
                #pragma unroll
                for (int nf = 0; nf < 4; ++nf)
                    #pragma unroll
                    for (int kk = 0; kk < 2; ++kk)
                        acc[mf][nf] = __builtin_amdgcn_mfma_f32_16x16x32_bf16(
                            a[mf][kk], bfr[nf][kk], acc[mf][nf], 0, 0, 0);
            __builtin_amdgcn_s_setprio(0);
            __builtin_amdgcn_s_barrier();   // bar1: B region consumed

            // pB: stage B(t+2); read A-mh1; MFMA Q(1,*) x32
            if (pf) { STAGE_B(ktp, base); }
            #pragma unroll
            for (int mf = 0; mf < 4; ++mf) {
                a[mf][0] = *(const short8*)(base + (aRow + (mf + 4) * 16) * 64 + xo0);
                a[mf][1] = *(const short8*)(base + (aRow + (mf + 4) * 16) * 64 + xo1);
            }
            __builtin_amdgcn_s_setprio(1);
            #pragma unroll
            for (int mf = 0; mf < 4; ++mf)
                #pragma unroll
                for (int nf = 0; nf < 4; ++nf)
                    #pragma unroll
                    for (int kk = 0; kk < 2; ++kk)
                        acc[4 + mf][nf] = __builtin_amdgcn_mfma_f32_16x16x32_bf16(
                            a[mf][kk], bfr[nf][kk], acc[4 + mf][nf], 0, 0, 0);
            __builtin_amdgcn_s_setprio(0);
            __builtin_amdgcn_s_barrier();   // bar2: A region consumed

            // pC: stage A(t+2); counted wait for tile t+1; barrier
            if (t + 1 < NT) {
                if (pf) {
                    STAGE_A(ktp, base);
                    asm volatile("s_waitcnt vmcnt(8)" ::: "memory");
                } else {
                    asm volatile("s_waitcnt vmcnt(0)" ::: "memory");
                }
                __builtin_amdgcn_s_barrier();   // bar3
            }
        }

        const int row0 = bm * 256 + wrow * 128 + lhi * 4;
        const int col0 = bn * 256 + wcol * 64 + l15;
        #pragma unroll
        for (int mf = 0; mf < 8; ++mf)
            #pragma unroll
            for (int nf = 0; nf < 4; ++nf)
                #pragma unroll
                for (int r = 0; r < 4; ++r)
                    z1[(size_t)(row0 + mf * 16 + r) * N + col0 + nf * 16] = f2bf(acc[mf][nf][r]);

        float s[4] = {0, 0, 0, 0}, sq[4] = {0, 0, 0, 0};
        #pragma unroll
        for (int mf = 0; mf < 8; ++mf)
            #pragma unroll
            for (int nf = 0; nf < 4; ++nf)
                #pragma unroll
                for (int r = 0; r < 4; ++r) {
                    float v = acc[mf][nf][r];
                    s[nf] += v; sq[nf] += v * v;
                }
        #pragma unroll
        for (int nf = 0; nf < 4; ++nf) {
            s[nf] += __shfl_xor(s[nf], 16); s[nf] += __shfl_xor(s[nf], 32);
            sq[nf] += __shfl_xor(sq[nf], 16); sq[nf] += __shfl_xor(sq[nf], 32);
        }
        if (lane < 16) {
            #pragma unroll
            for (int nf = 0; nf < 4; ++nf) {
                atomicAdd(&sums1[col0 + nf * 16], s[nf]);
                atomicAdd(&sqs1[col0 + nf * 16], sq[nf]);
            }
        }
        #undef STAGE_A
        #undef STAGE_B
    }

    grid.sync();

    // ======================= PHASE 2: gemm2 (2 tiles/block) =======================
    // A = relu(BN1(z1)) reg-staged+transformed in flight, B double-buffered via
    // global_load_lds with counted vmcnt(4), XOR swizzle, setprio, BN2 stats.
    {
        const int K = 1024, N = 512;
        const int NT = 16;
        float* a1s = (float*)(smem + 98304);
        float* b1s = a1s + 1024;
        // BN1 coefficients (whole block)
        for (int c = tid; c < 1024; c += 512) {
            float mu = sums1[c] * invB;
            float var = sqs1[c] * invB - mu * mu;
            float sc = g1[c] * rsqrtf(var + 1e-5f);
            a1s[c] = sc;
            b1s[c] = be1[c] - mu * sc;
        }
        __syncthreads();

        const int half = tid >> 8;
        const int htid = tid & 255;
        unsigned short* AsH = (unsigned short*)(smem + half * 49152);          // 16384 B
        unsigned short* BsH = (unsigned short*)(smem + half * 49152 + 16384);  // 2 x 16384 B

        const int t2i = bid * 2 + half;                  // 0..511
        const int swzb = (t2i & 7) * 64 + (t2i >> 3);    // cpx = 512/8 = 64
        const int bm = swzb >> 2, bn = swzb & 3;         // nbn = 4

        const int lane = htid & 63;
        const int wave = htid >> 6;                      // 0..3
        const int wr = (wave >> 1) << 6;
        const int wc = (wave & 1) << 6;

        const int srow = htid >> 3;                      // 0..31
        const int sca  = (htid & 7) ^ (srow & 7);
        const int acol = (htid & 7) * 8;
        const unsigned short* Asrc = z1 + (size_t)(bm * 128 + srow) * K + acol;
        const unsigned short* Bsrc = w2t + (size_t)(bn * 128 + srow) * K + sca * 8;

        #define STAGE_B2(kt, b)                                                     \
            _Pragma("unroll")                                                       \
            for (int i_ = 0; i_ < 4; ++i_)                                          \
                __builtin_amdgcn_global_load_lds(                                   \
                    (const __attribute__((address_space(1))) void*)(Bsrc + (size_t)(i_ * 32) * K + (kt)), \
                    (__attribute__((address_space(3))) void*)(BsH + (b) * 8192 + htid * 8 + i_ * 2048), 16, 0, 0);

        const int l15 = lane & 15, l7 = lane & 7, lhi = lane >> 4;
        const int xo0 = 8 * (lhi ^ l7);
        const int xo1 = 8 * ((lhi + 4) ^ l7);

        f32x4 acc[4][4];
        #pragma unroll
        for (int m = 0; m < 4; ++m)
            #pragma unroll
            for (int n = 0; n < 4; ++n) acc[m][n] = (f32x4){0.f, 0.f, 0.f, 0.f};

        STAGE_B2(0, 0);
        u16x8 va[4];
        #pragma unroll
        for (int i = 0; i < 4; ++i)
            va[i] = *(const u16x8*)(Asrc + (size_t)(i * 32) * K);

        for (int t = 0; t < NT; ++t) {
            const int cur = t & 1;
            const int kt = t << 6;
            const bool pf = (t + 1) < NT;
            if (pf) { STAGE_B2(kt + 64, cur ^ 1); }
            if (pf) asm volatile("s_waitcnt vmcnt(4)" ::: "memory");
            else    asm volatile("s_waitcnt vmcnt(0)" ::: "memory");

            {
                const int c0 = kt + acol;
                float av[8], bv[8];
                #pragma unroll
                for (int jj = 0; jj < 8; ++jj) { av[jj] = a1s[c0 + jj]; bv[jj] = b1s[c0 + jj]; }
                #pragma unroll
                for (int i = 0; i < 4; ++i) {
                    short8 w;
                    #pragma unroll
                    for (int jj = 0; jj < 8; ++jj)
                        w[jj] = (short)f2bf(fmaxf(av[jj] * bf2f(va[i][jj]) + bv[jj], 0.f));
                    *(short8*)&AsH[(srow + i * 32) * 64 + 8 * sca] = w;
                }
            }
            if (pf) {
                #pragma unroll
                for (int i = 0; i < 4; ++i)
                    va[i] = *(const u16x8*)(Asrc + (size_t)(i * 32) * K + kt + 64);
            }
            asm volatile("s_waitcnt lgkmcnt(0)" ::: "memory");
            __builtin_amdgcn_s_barrier();
            __builtin_amdgcn_sched_barrier(0);

            const unsigned short* bb = BsH + cur * 8192;
            short8 af[4][2], bfv[4][2];
            #pragma unroll
            for (int m = 0; m < 4; ++m) {
                af[m][0] = *(const short8*)&AsH[(wr + m * 16 + l15) * 64 + xo0];
                af[m][1] = *(const short8*)&AsH[(wr + m * 16 + l15) * 64 + xo1];
            }
            #pragma unroll
            for (int n = 0; n < 4; ++n) {
                bfv[n][0] = *(const short8*)(bb + (wc + n * 16 + l15) * 64 + xo0);
                bfv[n][1] = *(const short8*)(bb + (wc + n * 16 + l15) * 64 + xo1);
            }
            __builtin_amdgcn_s_setprio(1);
            #pragma unroll
            for (int m = 0; m < 4; ++m)
                #pragma unroll
                for (int n = 0; n < 4; ++n)
                    #pragma unroll
                    for (int kk = 0; kk < 2; ++kk)
                        acc[m][n] = __builtin_amdgcn_mfma_f32_16x16x32_bf16(
                            af[m][kk], bfv[n][kk], acc[m][n], 0, 0, 0);
            __builtin_amdgcn_s_setprio(0);
            __builtin_amdgcn_s_barrier();
        }

        const int row0 = bm * 128 + wr + lhi * 4;
        const int col0 = bn * 128 + wc + l15;
        #pragma unroll
        for (int m = 0; m < 4; ++m)
            #pragma unroll
            for (int n = 0; n < 4; ++n)
                #pragma unroll
                for (int r = 0; r < 4; ++r)
                    z2[(size_t)(row0 + m * 16 + r) * N + col0 + n * 16] = f2bf(acc[m][n][r]);

        float s[4] = {0, 0, 0, 0}, q[4] = {0, 0, 0, 0};
        #pragma unroll
        for (int m = 0; m < 4; ++m)
            #pragma unroll
            for (int n = 0; n < 4; ++n)
                #pragma unroll
                for (int r = 0; r < 4; ++r) {
                    float v = acc[m][n][r];
                    s[n] += v; q[n] += v * v;
                }
        #pragma unroll
        for (int n = 0; n < 4; ++n) {
            s[n] += __shfl_xor(s[n], 16); s[n] += __shfl_xor(s[n], 32);
            q[n] += __shfl_xor(q[n], 16); q[n] += __shfl_xor(q[n], 32);
        }
        if (lane < 16) {
            #pragma unroll
            for (int n = 0; n < 4; ++n) {
                atomicAdd(&sums2[col0 + n * 16], s[n]);
                atomicAdd(&sqs2[col0 + n * 16], q[n]);
            }
        }
        #undef STAGE_B2
    }

    grid.sync();

    // ======================= PHASE 3: final =======================
    {
        const int lane = tid & 63;
        const int w = tid >> 6;
        const int c = lane * 8;
        #pragma unroll
        for (int it = 0; it < 8; ++it) {
            int row = bid * 64 + it * 8 + w;
            u16x8 u = *(const u16x8*)&z2[(size_t)row * 512 + c];
            float dot = 0.f;
            #pragma unroll
            for (int j = 0; j < 8; ++j) {
                float mu = sums2[c + j] * invB;
                float var = sqs2[c + j] * invB - mu * mu;
                float a = g2[c + j] * rsqrtf(var + 1e-5f);
                float b = be2[c + j] - mu * a;
                float x = a * bf2f(u[j]) + b;
                dot += fmaxf(x, 0.f) * W3[c + j];
            }
            #pragma unroll
            for (int off = 32; off; off >>= 1) dot += __shfl_xor(dot, off);
            if (lane == 0) {
                float logit = fm[row] + dot + b3[0];
                float p = 1.f / (1.f + expf(-logit));
                out[row * 2 + 0] = 1.f - p;
                out[row * 2 + 1] = p;
            }
        }
    }
}

// ---------------------------------------------------------------------------
extern "C" void kernel_launch(void* const* d_in, const int* in_sizes, int n_in,
                              void* d_out, int out_size, void* d_ws, size_t ws_size,
                              hipStream_t stream)
{
    const int*   cat  = (const int*)d_in[0];
    const float* cont = (const float*)d_in[1];
    const float* bias = (const float*)d_in[2];
    const float* t1c  = (const float*)d_in[3];
    const float* t2c  = (const float*)d_in[4];
    const float* t1x  = (const float*)d_in[5];
    const float* t2x  = (const float*)d_in[6];
    const float* W1   = (const float*)d_in[7];
    // d_in[8] = b1: cancels under training-mode BN
    const float* g1   = (const float*)d_in[9];
    const float* be1  = (const float*)d_in[10];
    const float* W2   = (const float*)d_in[11];
    // d_in[12] = b2: cancels
    const float* g2   = (const float*)d_in[13];
    const float* be2  = (const float*)d_in[14];
    const float* W3   = (const float*)d_in[15];
    const float* b3   = (const float*)d_in[16];
    float* out = (float*)d_out;

    const int B = 16384, H1 = 1024, H2 = 512;

    uint8_t* p = (uint8_t*)d_ws;
    auto carve = [&](size_t bytes) {
        uint8_t* r = p;
        p += (bytes + 255) & ~(size_t)255;
        return r;
    };
    unsigned short* deep = (unsigned short*)carve((size_t)B * KP * 2);   // 56.6 MB
    unsigned short* w1t  = (unsigned short*)carve((size_t)H1 * KP * 2);
    unsigned short* w2t  = (unsigned short*)carve((size_t)H2 * H1 * 2);
    unsigned short* z1   = (unsigned short*)carve((size_t)B * H1 * 2);
    unsigned short* z2   = (unsigned short*)carve((size_t)B * H2 * 2);
    float* fm    = (float*)carve((size_t)B * 4);
    float* stats = (float*)carve((size_t)3072 * 4);

    void* args[] = {
        (void*)&cat, (void*)&cont, (void*)&bias, (void*)&t1c, (void*)&t2c,
        (void*)&t1x, (void*)&t2x, (void*)&W1, (void*)&g1, (void*)&be1,
        (void*)&W2, (void*)&g2, (void*)&be2, (void*)&W3, (void*)&b3,
        (void*)&deep, (void*)&fm, (void*)&w1t, (void*)&w2t,
        (void*)&z1, (void*)&z2, (void*)&stats, (void*)&out
    };
    hipLaunchCooperativeKernel((const void*)mega, dim3(256), dim3(512),
                               args, 0, stream);
}

// Round 10
// 145.129 us; speedup vs baseline: 1.7687x; 1.7687x over previous
//
#include <hip/hip_runtime.h>
#include <stdint.h>

typedef __attribute__((ext_vector_type(8))) short short8;
typedef __attribute__((ext_vector_type(8))) unsigned short u16x8;
typedef __attribute__((ext_vector_type(4))) float f32x4;

#define DEV __device__ __forceinline__

DEV float bf2f(unsigned short v) {
    union { unsigned int u; float f; } c;
    c.u = ((unsigned int)v) << 16;
    return c.f;
}
DEV unsigned short f2bf(float f) {
    union { float f; unsigned int u; } c;
    c.f = f;
    unsigned int x = c.u;
    x += 0x7fffu + ((x >> 16) & 1u);   // round-to-nearest-even
    return (unsigned short)(x >> 16);
}

// K layout: cols 0..1663 = 26 cat embeddings (26x64); cols 1664..1676 = raw
// cont features (rank-13 folding); cols 1677..1727 = zero.  KP = 1728 = 27*64.
#define KCAT 1664
#define KP   1728

// ---------------------------------------------------------------------------
// FRONT kernel (one dispatch, 3 independent jobs selected by blockIdx):
//   blocks 0..4095        : embedding gather + FM + deep write
//   blocks 4096..6271     : transpose+cast W1-top (1664) / W2 (512)
//   blocks 6272..6323     : rank-13 cont fold P[n,f] into w1t tail + zero pad
//   block  6324           : zero the 3072-float stats buffer
// NOTE: 256-thr blocks, small LDS -> ~8 blocks/CU; the gather phase is
// latency-bound and needs this occupancy (R9 mega-kernel lesson).
// ---------------------------------------------------------------------------
#define NB_EMB 4096
#define NB_TR  2176
#define NB_FLD 52

__global__ __launch_bounds__(256) void front_k(
    const int* __restrict__ cat, const float* __restrict__ cont,
    const float* __restrict__ bias,
    const float* __restrict__ t1c, const float* __restrict__ t2c,
    const float* __restrict__ t1x, const float* __restrict__ t2x,
    unsigned short* __restrict__ deep, float* __restrict__ fm,
    const float* __restrict__ W1, unsigned short* __restrict__ w1t,
    const float* __restrict__ W2, unsigned short* __restrict__ w2t,
    float* __restrict__ stats)
{
    __shared__ __align__(16) unsigned char smem[4 * KP * 2];   // 13824 B
    const int tid = threadIdx.x;
    int b = blockIdx.x;

    if (b < NB_EMB) {
        // ---------------- embedding + FM ----------------
        unsigned short (*rowbuf)[KP] = (unsigned short (*)[KP])smem;
        const int ty = tid >> 6;
        const int d = tid & 63;
        const int row = b * 4 + ty;
        const int* crow = cat + row * 26;
        const float* xrow = cont + row * 13;

        float s = 0.f, ss = 0.f;
        #pragma unroll
        for (int f = 0; f < 26; ++f) {
            int idx = crow[f];                                  // wave-uniform
            float e = t2c[((size_t)f * 100000 + idx) * 64 + d]; // coalesced 256B
            s += e; ss += e * e;
            rowbuf[ty][f * 64 + d] = f2bf(e);
        }
        #pragma unroll
        for (int f = 0; f < 13; ++f) {
            float x = xrow[f];
            float e = t2x[f * 64 + d] * x;
            s += e; ss += e * e;
        }
        rowbuf[ty][KCAT + d] = (d < 13) ? f2bf(xrow[d]) : (unsigned short)0;

        float val = 0.5f * (s * s - ss);
        if (d < 26) val += t1c[(size_t)d * 100000 + crow[d]];
        if (d < 13) val += t1x[d] * xrow[d];
        #pragma unroll
        for (int off = 32; off; off >>= 1) val += __shfl_xor(val, off);
        if (d == 0) fm[row] = bias[0] + val;

        __syncthreads();
        const unsigned short* src = (const unsigned short*)smem;
        unsigned short* dst = deep + (size_t)(b * 4) * KP;
        #pragma unroll
        for (int it = 0; it < 4; ++it) {
            int off = it * 2048 + tid * 8;
            if (off < 4 * KP)
                *(u16x8*)(dst + off) = *(const u16x8*)(src + off);
        }
    } else if (b < NB_EMB + NB_TR) {
        // ---------------- W transpose + bf16 cast ----------------
        float (*tile)[33] = (float (*)[33])smem;
        b -= NB_EMB;
        const float* in; unsigned short* out; int C, KO, bx, by;
        if (b < 1664) { in = W1; out = w1t; C = 1024; KO = KP; bx = b & 31; by = b >> 5; }
        else { b -= 1664; in = W2; out = w2t; C = 512; KO = 1024; bx = b & 15; by = b >> 4; }
        int c0 = bx * 32, r0 = by * 32;
        int tx = tid & 31, ty = tid >> 5;
        #pragma unroll
        for (int i = 0; i < 4; ++i)
            tile[ty + i * 8][tx] = in[(size_t)(r0 + ty + i * 8) * C + c0 + tx];
        __syncthreads();
        #pragma unroll
        for (int i = 0; i < 4; ++i)
            out[(size_t)(c0 + ty + i * 8) * KO + r0 + tx] = f2bf(tile[tx][ty + i * 8]);
    } else if (b < NB_EMB + NB_TR + NB_FLD) {
        // ---------------- rank-13 cont fold into w1t tail ----------------
        b -= NB_EMB + NB_TR;                       // 0..51
        int f = b >> 2;                            // 0..12
        int n = (b & 3) * 256 + tid;               // 0..1023
        float s = 0.f;
        #pragma unroll 8
        for (int d = 0; d < 64; ++d)
            s += W1[(size_t)(KCAT + f * 64 + d) * 1024 + n] * t2x[f * 64 + d];
        w1t[(size_t)n * KP + KCAT + f] = f2bf(s);
        if (f == 0)
            for (int j = KCAT + 13; j < KP; ++j)
                w1t[(size_t)n * KP + j] = 0;
    } else {
        // ---------------- zero stats (3072 floats) ----------------
        #pragma unroll
        for (int i = 0; i < 12; ++i)
            stats[i * 256 + tid] = 0.f;
    }
}

// ---------------------------------------------------------------------------
// GEMM1: 256x256-tile 8-wave bf16 GEMM, counted-vmcnt pipeline (raw s_barrier),
// LDS XOR swizzle, setprio, XCD-chunked block swizzle, fused column stats.
// (unchanged from R8: 142.7 us total)
// ---------------------------------------------------------------------------
__global__ __launch_bounds__(512, 2) void gemm256(
    const unsigned short* __restrict__ A,
    const unsigned short* __restrict__ Bt,
    unsigned short* __restrict__ C,
    float* __restrict__ sums, float* __restrict__ sqs,
    int M, int N, int K)
{
    __shared__ unsigned short lds[2][32768];   // [buf][A:0..16384 | B:16384..32768]
    const int tid = threadIdx.x;
    const int lane = tid & 63, wid = tid >> 6;
    const int wrow = wid >> 2, wcol = wid & 3;
    const int nbn = N >> 8;
    const int cpx = gridDim.x >> 3;
    const int swzb = (blockIdx.x & 7) * cpx + (blockIdx.x >> 3);
    const int bm = swzb / nbn, bn = swzb % nbn;
    const int NT = K >> 6;

    const int srow = tid >> 3;
    const int skc  = (tid & 7) ^ (srow & 7);
    const unsigned short* Asrc = A + (size_t)(bm * 256 + srow) * K + skc * 8;
    const unsigned short* Bsrc = Bt + (size_t)(bn * 256 + srow) * K + skc * 8;

    #define STAGE_A(kt, b)                                                        \
        _Pragma("unroll")                                                         \
        for (int i_ = 0; i_ < 4; ++i_)                                            \
            __builtin_amdgcn_global_load_lds(                                     \
                (const __attribute__((address_space(1))) void*)(Asrc + (size_t)(i_ * 64) * K + (kt)), \
                (__attribute__((address_space(3))) void*)(&lds[b][tid * 8 + i_ * 4096]), 16, 0, 0);
    #define STAGE_B(kt, b)                                                        \
        _Pragma("unroll")                                                         \
        for (int i_ = 0; i_ < 4; ++i_)                                            \
            __builtin_amdgcn_global_load_lds(                                     \
                (const __attribute__((address_space(1))) void*)(Bsrc + (size_t)(i_ * 64) * K + (kt)), \
                (__attribute__((address_space(3))) void*)(&lds[b][16384 + tid * 8 + i_ * 4096]), 16, 0, 0);

    const int l15 = lane & 15, l7 = lane & 7, lhi = lane >> 4;
    const int xo0 = 8 * (lhi ^ l7);
    const int xo1 = 8 * ((lhi + 4) ^ l7);
    const int aRow = wrow * 128 + l15;
    const int bRow = wcol * 64 + l15;

    f32x4 acc[8][4];
    #pragma unroll
    for (int m = 0; m < 8; ++m)
        #pragma unroll
        for (int n = 0; n < 4; ++n) acc[m][n] = (f32x4){0.f, 0.f, 0.f, 0.f};

    STAGE_A(0, 0); STAGE_B(0, 0);
    STAGE_A(64, 1); STAGE_B(64, 1);
    asm volatile("s_waitcnt vmcnt(8)" ::: "memory");
    __builtin_amdgcn_s_barrier();

    for (int t = 0; t < NT; ++t) {
        const int cb = t & 1;
        const unsigned short* base = &lds[cb][0];
        const int ktp = (t + 2) << 6;
        const bool pf = (t + 2) < NT;

        short8 a[4][2], bfr[4][2];
        // pA: read A-mh0 + all B; MFMA Q(0,*) x32
        #pragma unroll
        for (int mf = 0; mf < 4; ++mf) {
            a[mf][0] = *(const short8*)(base + (aRow + mf * 16) * 64 + xo0);
            a[mf][1] = *(const short8*)(base + (aRow + mf * 16) * 64 + xo1);
        }
        #pragma unroll
        for (int nf = 0; nf < 4; ++nf) {
            bfr[nf][0] = *(const short8*)(base + 16384 + (bRow + nf * 16) * 64 + xo0);
            bfr[nf][1] = *(const short8*)(base + 16384 + (bRow + nf * 16) * 64 + xo1);
        }
        __builtin_amdgcn_s_setprio(1);
        #pragma unroll
        for (int mf = 0; mf < 4; ++mf)
            #pragma unroll
            for (int nf = 0; nf < 4; ++nf)
                #pragma unroll
                for (int kk = 0; kk < 2; ++kk)
                    acc[mf][nf] = __builtin_amdgcn_mfma_f32_16x16x32_bf16(
                        a[mf][kk], bfr[nf][kk], acc[mf][nf], 0, 0, 0);
        __builtin_amdgcn_s_setprio(0);
        __builtin_amdgcn_s_barrier();   // bar1: B region consumed

        // pB: stage B(t+2); read A-mh1; MFMA Q(1,*) x32
        if (pf) { STAGE_B(ktp, cb); }
        #pragma unroll
        for (int mf = 0; mf < 4; ++mf) {
            a[mf][0] = *(const short8*)(base + (aRow + (mf + 4) * 16) * 64 + xo0);
            a[mf][1] = *(const short8*)(base + (aRow + (mf + 4) * 16) * 64 + xo1);
        }
        __builtin_amdgcn_s_setprio(1);
        #pragma unroll
        for (int mf = 0; mf < 4; ++mf)
            #pragma unroll
            for (int nf = 0; nf < 4; ++nf)
                #pragma unroll
                for (int kk = 0; kk < 2; ++kk)
                    acc[4 + mf][nf] = __builtin_amdgcn_mfma_f32_16x16x32_bf16(
                        a[mf][kk], bfr[nf][kk], acc[4 + mf][nf], 0, 0, 0);
        __builtin_amdgcn_s_setprio(0);
        __builtin_amdgcn_s_barrier();   // bar2: A region consumed

        // pC: stage A(t+2); counted wait for tile t+1; barrier
        if (t + 1 < NT) {
            if (pf) {
                STAGE_A(ktp, cb);
                asm volatile("s_waitcnt vmcnt(8)" ::: "memory");
            } else {
                asm volatile("s_waitcnt vmcnt(0)" ::: "memory");
            }
            __builtin_amdgcn_s_barrier();   // bar3
        }
    }

    const int row0 = bm * 256 + wrow * 128 + lhi * 4;
    const int col0 = bn * 256 + wcol * 64 + l15;
    #pragma unroll
    for (int mf = 0; mf < 8; ++mf)
        #pragma unroll
        for (int nf = 0; nf < 4; ++nf)
            #pragma unroll
            for (int r = 0; r < 4; ++r)
                C[(size_t)(row0 + mf * 16 + r) * N + col0 + nf * 16] = f2bf(acc[mf][nf][r]);

    float s[4] = {0, 0, 0, 0}, sq[4] = {0, 0, 0, 0};
    #pragma unroll
    for (int mf = 0; mf < 8; ++mf)
        #pragma unroll
        for (int nf = 0; nf < 4; ++nf)
            #pragma unroll
            for (int r = 0; r < 4; ++r) {
                float v = acc[mf][nf][r];
                s[nf] += v; sq[nf] += v * v;
            }
    #pragma unroll
    for (int nf = 0; nf < 4; ++nf) {
        s[nf] += __shfl_xor(s[nf], 16); s[nf] += __shfl_xor(s[nf], 32);
        sq[nf] += __shfl_xor(sq[nf], 16); sq[nf] += __shfl_xor(sq[nf], 32);
    }
    if (lane < 16) {
        #pragma unroll
        for (int nf = 0; nf < 4; ++nf) {
            atomicAdd(&sums[col0 + nf * 16], s[nf]);
            atomicAdd(&sqs[col0 + nf * 16], sq[nf]);
        }
    }
    #undef STAGE_A
    #undef STAGE_B
}

// ---------------------------------------------------------------------------
// GEMM2: 128x256 tiles (nbn=2: halves the redundant BN1-transform VALU and
// the z1 re-read vs the old 128x128/nbn=4).  512 thr, 8 waves (2M x 4N),
// grid = 128 x 2 = 256 blocks (1/CU).  A = relu(BN1(z1)) reg-staged +
// transformed in flight (1 tile ahead); B double-buffered via global_load_lds
// with counted vmcnt(4); XOR-swizzled As/Bs; setprio; fused BN2 stats.
// ---------------------------------------------------------------------------
__global__ __launch_bounds__(512, 2) void gemm2_fused(
    const unsigned short* __restrict__ z1,
    const unsigned short* __restrict__ Bt,
    unsigned short* __restrict__ C,
    const float* __restrict__ sums1, const float* __restrict__ sqs1,
    const float* __restrict__ g1, const float* __restrict__ be1,
    float* __restrict__ sums2, float* __restrict__ sqs2,
    int M, int N, int K, float invB)
{
    __shared__ unsigned short As[128 * 64];        // 16 KiB
    __shared__ unsigned short Bs[2][256 * 64];     // 64 KiB
    __shared__ float a1s[1024], b1s[1024];         //  8 KiB
    const int tid = threadIdx.x;
    const int lane = tid & 63;
    const int wave = tid >> 6;                     // 0..7
    const int cpx = gridDim.x >> 3;                // 32
    const int swzb = (blockIdx.x & 7) * cpx + (blockIdx.x >> 3);
    const int bm = swzb >> 1, bn = swzb & 1;       // nbn = 2
    const int NT = K >> 6;                         // 16
    const int wr = (wave >> 2) << 6;               // 0,64
    const int wc = (wave & 3) << 6;                // 0,64,128,192

    // BN1 coefficients from raw stats (folded bn1_coeff)
    for (int c = tid; c < 1024; c += 512) {
        float mu = sums1[c] * invB;
        float var = sqs1[c] * invB - mu * mu;
        float sc = g1[c] * rsqrtf(var + 1e-5f);
        a1s[c] = sc;
        b1s[c] = be1[c] - mu * sc;
    }
    __syncthreads();   // coeffs visible before staging

    const int srow = tid >> 3;                     // 0..63
    const int sca  = (tid & 7) ^ (srow & 7);       // swizzled chunk
    const int acol = (tid & 7) * 8;
    const unsigned short* Asrc = z1 + (size_t)(bm * 128 + srow) * K + acol;
    const unsigned short* Bsrc = Bt + (size_t)(bn * 256 + srow) * K + sca * 8;

    // B: 256 rows x 64 cols staged by 512 thr -> 4 gload_lds/thread
    #define STAGE_B2(kt, b)                                                     \
        _Pragma("unroll")                                                       \
        for (int i_ = 0; i_ < 4; ++i_)                                          \
            __builtin_amdgcn_global_load_lds(                                   \
                (const __attribute__((address_space(1))) void*)(Bsrc + (size_t)(i_ * 64) * K + (kt)), \
                (__attribute__((address_space(3))) void*)(&Bs[b][tid * 8 + i_ * 4096]), 16, 0, 0);

    const int l15 = lane & 15, l7 = lane & 7, lhi = lane >> 4;
    const int xo0 = 8 * (lhi ^ l7);
    const int xo1 = 8 * ((lhi + 4) ^ l7);

    f32x4 acc[4][4];
    #pragma unroll
    for (int m = 0; m < 4; ++m)
        #pragma unroll
        for (int n = 0; n < 4; ++n) acc[m][n] = (f32x4){0.f, 0.f, 0.f, 0.f};

    // prologue: B(0) staged (4 loads), A(0) reg loads issued (2 loads)
    STAGE_B2(0, 0);
    u16x8 va[2];
    #pragma unroll
    for (int i = 0; i < 2; ++i)
        va[i] = *(const u16x8*)(Asrc + (size_t)(i * 64) * K);

    for (int t = 0; t < NT; ++t) {
        const int cur = t & 1;
        const int kt = t << 6;
        const bool pf = (t + 1) < NT;
        if (pf) { STAGE_B2(kt + 64, cur ^ 1); }
        // outstanding oldest->newest: B(t)x4, A(t)x2, [B(t+1)x4]
        if (pf) asm volatile("s_waitcnt vmcnt(4)" ::: "memory");
        else    asm volatile("s_waitcnt vmcnt(0)" ::: "memory");

        // BN1 + ReLU transform -> swizzled ds_write (16 elems/thread)
        {
            const int c0 = kt + acol;
            float av[8], bv[8];
            #pragma unroll
            for (int jj = 0; jj < 8; ++jj) { av[jj] = a1s[c0 + jj]; bv[jj] = b1s[c0 + jj]; }
            #pragma unroll
            for (int i = 0; i < 2; ++i) {
                short8 w;
                #pragma unroll
                for (int jj = 0; jj < 8; ++jj)
                    w[jj] = (short)f2bf(fmaxf(av[jj] * bf2f(va[i][jj]) + bv[jj], 0.f));
                *(short8*)&As[(srow + i * 64) * 64 + 8 * sca] = w;
            }
        }
        if (pf) {
            #pragma unroll
            for (int i = 0; i < 2; ++i)
                va[i] = *(const u16x8*)(Asrc + (size_t)(i * 64) * K + kt + 64);
        }
        asm volatile("s_waitcnt lgkmcnt(0)" ::: "memory");
        __builtin_amdgcn_s_barrier();
        __builtin_amdgcn_sched_barrier(0);

        const unsigned short* bb = &Bs[cur][0];
        short8 af[4][2], bfv[4][2];
        #pragma unroll
        for (int m = 0; m < 4; ++m) {
            af[m][0] = *(const short8*)&As[(wr + m * 16 + l15) * 64 + xo0];
            af[m][1] = *(const short8*)&As[(wr + m * 16 + l15) * 64 + xo1];
        }
        #pragma unroll
        for (int n = 0; n < 4; ++n) {
            bfv[n][0] = *(const short8*)(bb + (wc + n * 16 + l15) * 64 + xo0);
            bfv[n][1] = *(const short8*)(bb + (wc + n * 16 + l15) * 64 + xo1);
        }
        __builtin_amdgcn_s_setprio(1);
        #pragma unroll
        for (int m = 0; m < 4; ++m)
            #pragma unroll
            for (int n = 0; n < 4; ++n)
                #pragma unroll
                for (int kk = 0; kk < 2; ++kk)
                    acc[m][n] = __builtin_amdgcn_mfma_f32_16x16x32_bf16(
                        af[m][kk], bfv[n][kk], acc[m][n], 0, 0, 0);
        __builtin_amdgcn_s_setprio(0);
        __builtin_amdgcn_s_barrier();   // As / Bs[cur] consumed by all waves
    }

    const int row0 = bm * 128 + wr + lhi * 4;
    const int col0 = bn * 256 + wc + l15;
    #pragma unroll
    for (int m = 0; m < 4; ++m)
        #pragma unroll
        for (int n = 0; n < 4; ++n)
            #pragma unroll
            for (int r = 0; r < 4; ++r)
                C[(size_t)(row0 + m * 16 + r) * N + col0 + n * 16] = f2bf(acc[m][n][r]);

    float s[4] = {0, 0, 0, 0}, q[4] = {0, 0, 0, 0};
    #pragma unroll
    for (int m = 0; m < 4; ++m)
        #pragma unroll
        for (int n = 0; n < 4; ++n)
            #pragma unroll
            for (int r = 0; r < 4; ++r) {
                float v = acc[m][n][r];
                s[n] += v; q[n] += v * v;
            }
    #pragma unroll
    for (int n = 0; n < 4; ++n) {
        s[n] += __shfl_xor(s[n], 16); s[n] += __shfl_xor(s[n], 32);
        q[n] += __shfl_xor(q[n], 16); q[n] += __shfl_xor(q[n], 32);
    }
    if (lane < 16) {
        #pragma unroll
        for (int n = 0; n < 4; ++n) {
            atomicAdd(&sums2[col0 + n * 16], s[n]);
            atomicAdd(&sqs2[col0 + n * 16], q[n]);
        }
    }
    #undef STAGE_B2
}

// ---------------------------------------------------------------------------
// Final: BN2 (coeffs from raw stats) + ReLU + dot(W3) + b3 + fm -> sigmoid
// ---------------------------------------------------------------------------
__global__ __launch_bounds__(256) void final_k(
    const unsigned short* __restrict__ z2,
    const float* __restrict__ sums2, const float* __restrict__ sqs2,
    const float* __restrict__ g2, const float* __restrict__ be2,
    const float* __restrict__ W3, const float* __restrict__ b3,
    const float* __restrict__ fm, float* __restrict__ out, float invB)
{
    int row = blockIdx.x * 4 + threadIdx.y;
    int lane = threadIdx.x;
    int c = lane * 8;
    u16x8 u = *(const u16x8*)&z2[(size_t)row * 512 + c];
    float dot = 0.f;
    #pragma unroll
    for (int j = 0; j < 8; ++j) {
        float mu = sums2[c + j] * invB;
        float var = sqs2[c + j] * invB - mu * mu;
        float a = g2[c + j] * rsqrtf(var + 1e-5f);
        float b = be2[c + j] - mu * a;
        float x = a * bf2f(u[j]) + b;
        dot += fmaxf(x, 0.f) * W3[c + j];
    }
    #pragma unroll
    for (int off = 32; off; off >>= 1) dot += __shfl_xor(dot, off);
    if (lane == 0) {
        float logit = fm[row] + dot + b3[0];
        float p = 1.f / (1.f + expf(-logit));
        out[row * 2 + 0] = 1.f - p;
        out[row * 2 + 1] = p;
    }
}

// ---------------------------------------------------------------------------
extern "C" void kernel_launch(void* const* d_in, const int* in_sizes, int n_in,
                              void* d_out, int out_size, void* d_ws, size_t ws_size,
                              hipStream_t stream)
{
    const int*   cat  = (const int*)d_in[0];
    const float* cont = (const float*)d_in[1];
    const float* bias = (const float*)d_in[2];
    const float* t1c  = (const float*)d_in[3];
    const float* t2c  = (const float*)d_in[4];
    const float* t1x  = (const float*)d_in[5];
    const float* t2x  = (const float*)d_in[6];
    const float* W1   = (const float*)d_in[7];
    // d_in[8] = b1: cancels under training-mode BN
    const float* g1   = (const float*)d_in[9];
    const float* be1  = (const float*)d_in[10];
    const float* W2   = (const float*)d_in[11];
    // d_in[12] = b2: cancels
    const float* g2   = (const float*)d_in[13];
    const float* be2  = (const float*)d_in[14];
    const float* W3   = (const float*)d_in[15];
    const float* b3   = (const float*)d_in[16];
    float* out = (float*)d_out;

    const int B = 16384, H1 = 1024, H2 = 512;

    uint8_t* p = (uint8_t*)d_ws;
    auto carve = [&](size_t bytes) {
        uint8_t* r = p;
        p += (bytes + 255) & ~(size_t)255;
        return r;
    };
    unsigned short* deep = (unsigned short*)carve((size_t)B * KP * 2);   // 56.6 MB
    unsigned short* w1t  = (unsigned short*)carve((size_t)H1 * KP * 2);
    unsigned short* w2t  = (unsigned short*)carve((size_t)H2 * H1 * 2);
    unsigned short* z1   = (unsigned short*)carve((size_t)B * H1 * 2);
    unsigned short* z2   = (unsigned short*)carve((size_t)B * H2 * 2);
    float* fm    = (float*)carve((size_t)B * 4);
    float* stats = (float*)carve((size_t)3072 * 4);
    float* sums1 = stats, *sqs1 = stats + H1, *sums2 = stats + 2 * H1, *sqs2 = stats + 2 * H1 + H2;

    // FRONT: embed+FM (4096) | W transposes (2176) | cont fold (52) | zero stats (1)
    front_k<<<NB_EMB + NB_TR + NB_FLD + 1, 256, 0, stream>>>(
        cat, cont, bias, t1c, t2c, t1x, t2x, deep, fm, W1, w1t, W2, w2t, stats);

    // GEMM1: K = 1728 (27 tiles), counted-vmcnt pipeline, fused BN1 stats
    gemm256<<<(B / 256) * (H1 / 256), 512, 0, stream>>>(deep, w1t, z1, sums1, sqs1, B, H1, KP);

    // GEMM2: 128x256 tiles (nbn=2), BN1 coeff+apply+ReLU fused, fused BN2 stats
    gemm2_fused<<<(B / 128) * (H2 / 256), 512, 0, stream>>>(
        z1, w2t, z2, sums1, sqs1, g1, be1, sums2, sqs2, B, H2, H1, 1.f / B);

    final_k<<<B / 4, dim3(64, 4), 0, stream>>>(z2, sums2, sqs2, g2, be2, W3, b3, fm, out, 1.f / B);
}

// Round 11
// 141.935 us; speedup vs baseline: 1.8085x; 1.0225x over previous
//
#include <hip/hip_runtime.h>
#include <stdint.h>

typedef __attribute__((ext_vector_type(8))) short short8;
typedef __attribute__((ext_vector_type(8))) unsigned short u16x8;
typedef __attribute__((ext_vector_type(4))) float f32x4;

#define DEV __device__ __forceinline__

DEV float bf2f(unsigned short v) {
    union { unsigned int u; float f; } c;
    c.u = ((unsigned int)v) << 16;
    return c.f;
}
DEV unsigned short f2bf(float f) {
    union { float f; unsigned int u; } c;
    c.f = f;
    unsigned int x = c.u;
    x += 0x7fffu + ((x >> 16) & 1u);   // round-to-nearest-even
    return (unsigned short)(x >> 16);
}

// K layout: cols 0..1663 = 26 cat embeddings (26x64); cols 1664..1676 = raw
// cont features (rank-13 folding); cols 1677..1727 = zero.  KP = 1728 = 27*64.
#define KCAT 1664
#define KP   1728

// ---------------------------------------------------------------------------
// FRONT kernel (one dispatch, 3 independent jobs selected by blockIdx):
//   blocks 0..4095        : embedding gather + FM + deep write
//   blocks 4096..6271     : transpose+cast W1-top (1664) / W2 (512)
//   blocks 6272..6323     : rank-13 cont fold P[n,f] into w1t tail + zero pad
//   block  6324           : zero the 3072-float stats buffer
// 256-thr blocks, small LDS -> ~8 blocks/CU (gather is latency-bound; R9
// mega-kernel at 1 block/CU regressed 80%).
// ---------------------------------------------------------------------------
#define NB_EMB 4096
#define NB_TR  2176
#define NB_FLD 52

__global__ __launch_bounds__(256) void front_k(
    const int* __restrict__ cat, const float* __restrict__ cont,
    const float* __restrict__ bias,
    const float* __restrict__ t1c, const float* __restrict__ t2c,
    const float* __restrict__ t1x, const float* __restrict__ t2x,
    unsigned short* __restrict__ deep, float* __restrict__ fm,
    const float* __restrict__ W1, unsigned short* __restrict__ w1t,
    const float* __restrict__ W2, unsigned short* __restrict__ w2t,
    float* __restrict__ stats)
{
    __shared__ __align__(16) unsigned char smem[4 * KP * 2];   // 13824 B
    const int tid = threadIdx.x;
    int b = blockIdx.x;

    if (b < NB_EMB) {
        // ---------------- embedding + FM ----------------
        unsigned short (*rowbuf)[KP] = (unsigned short (*)[KP])smem;
        const int ty = tid >> 6;
        const int d = tid & 63;
        const int row = b * 4 + ty;
        const int* crow = cat + row * 26;
        const float* xrow = cont + row * 13;

        float s = 0.f, ss = 0.f;
        #pragma unroll
        for (int f = 0; f < 26; ++f) {
            int idx = crow[f];                                  // wave-uniform
            float e = t2c[((size_t)f * 100000 + idx) * 64 + d]; // coalesced 256B
            s += e; ss += e * e;
            rowbuf[ty][f * 64 + d] = f2bf(e);
        }
        #pragma unroll
        for (int f = 0; f < 13; ++f) {
            float x = xrow[f];
            float e = t2x[f * 64 + d] * x;
            s += e; ss += e * e;
        }
        rowbuf[ty][KCAT + d] = (d < 13) ? f2bf(xrow[d]) : (unsigned short)0;

        float val = 0.5f * (s * s - ss);
        if (d < 26) val += t1c[(size_t)d * 100000 + crow[d]];
        if (d < 13) val += t1x[d] * xrow[d];
        #pragma unroll
        for (int off = 32; off; off >>= 1) val += __shfl_xor(val, off);
        if (d == 0) fm[row] = bias[0] + val;

        __syncthreads();
        const unsigned short* src = (const unsigned short*)smem;
        unsigned short* dst = deep + (size_t)(b * 4) * KP;
        #pragma unroll
        for (int it = 0; it < 4; ++it) {
            int off = it * 2048 + tid * 8;
            if (off < 4 * KP)
                *(u16x8*)(dst + off) = *(const u16x8*)(src + off);
        }
    } else if (b < NB_EMB + NB_TR) {
        // ---------------- W transpose + bf16 cast ----------------
        float (*tile)[33] = (float (*)[33])smem;
        b -= NB_EMB;
        const float* in; unsigned short* out; int C, KO, bx, by;
        if (b < 1664) { in = W1; out = w1t; C = 1024; KO = KP; bx = b & 31; by = b >> 5; }
        else { b -= 1664; in = W2; out = w2t; C = 512; KO = 1024; bx = b & 15; by = b >> 4; }
        int c0 = bx * 32, r0 = by * 32;
        int tx = tid & 31, ty = tid >> 5;
        #pragma unroll
        for (int i = 0; i < 4; ++i)
            tile[ty + i * 8][tx] = in[(size_t)(r0 + ty + i * 8) * C + c0 + tx];
        __syncthreads();
        #pragma unroll
        for (int i = 0; i < 4; ++i)
            out[(size_t)(c0 + ty + i * 8) * KO + r0 + tx] = f2bf(tile[tx][ty + i * 8]);
    } else if (b < NB_EMB + NB_TR + NB_FLD) {
        // ---------------- rank-13 cont fold into w1t tail ----------------
        b -= NB_EMB + NB_TR;                       // 0..51
        int f = b >> 2;                            // 0..12
        int n = (b & 3) * 256 + tid;               // 0..1023
        float s = 0.f;
        #pragma unroll 8
        for (int d = 0; d < 64; ++d)
            s += W1[(size_t)(KCAT + f * 64 + d) * 1024 + n] * t2x[f * 64 + d];
        w1t[(size_t)n * KP + KCAT + f] = f2bf(s);
        if (f == 0)
            for (int j = KCAT + 13; j < KP; ++j)
                w1t[(size_t)n * KP + j] = 0;
    } else {
        // ---------------- zero stats (3072 floats) ----------------
        #pragma unroll
        for (int i = 0; i < 12; ++i)
            stats[i * 256 + tid] = 0.f;
    }
}

// ---------------------------------------------------------------------------
// GEMM1: 256x256-tile 8-wave bf16 GEMM, counted-vmcnt 2-barrier pipeline.
// vs R8 (3-barrier): A-mh1 ds_reads hoisted into pA under the MFMA cluster
// (latency hidden; explicit lgkmcnt(0) before bar1 prevents reads crossing
// the barrier into the region pB's stages overwrite), and since after bar1
// no wave reads LDS, BOTH stages (A & B of t+2) issue together in pB.
//   pA: ds_read a(mh0) x8, b(all) x8, a2(mh1) x8; 32 MFMA Q(0,*);
//       lgkmcnt(0); bar1
//   pB: stage B(t+2) + A(t+2) -> buf[cb]; 32 MFMA Q(1,*) (regs only);
//       vmcnt(8) [drains t+1's 8, keeps t+2's 8 in flight]; bar2
// ---------------------------------------------------------------------------
__global__ __launch_bounds__(512, 2) void gemm256(
    const unsigned short* __restrict__ A,
    const unsigned short* __restrict__ Bt,
    unsigned short* __restrict__ C,
    float* __restrict__ sums, float* __restrict__ sqs,
    int M, int N, int K)
{
    __shared__ unsigned short lds[2][32768];   // [buf][A:0..16384 | B:16384..32768]
    const int tid = threadIdx.x;
    const int lane = tid & 63, wid = tid >> 6;
    const int wrow = wid >> 2, wcol = wid & 3;
    const int nbn = N >> 8;
    const int cpx = gridDim.x >> 3;
    const int swzb = (blockIdx.x & 7) * cpx + (blockIdx.x >> 3);
    const int bm = swzb / nbn, bn = swzb % nbn;
    const int NT = K >> 6;

    const int srow = tid >> 3;
    const int skc  = (tid & 7) ^ (srow & 7);
    const unsigned short* Asrc = A + (size_t)(bm * 256 + srow) * K + skc * 8;
    const unsigned short* Bsrc = Bt + (size_t)(bn * 256 + srow) * K + skc * 8;

    #define STAGE_A(kt, b)                                                        \
        _Pragma("unroll")                                                         \
        for (int i_ = 0; i_ < 4; ++i_)                                            \
            __builtin_amdgcn_global_load_lds(                                     \
                (const __attribute__((address_space(1))) void*)(Asrc + (size_t)(i_ * 64) * K + (kt)), \
                (__attribute__((address_space(3))) void*)(&lds[b][tid * 8 + i_ * 4096]), 16, 0, 0);
    #define STAGE_B(kt, b)                                                        \
        _Pragma("unroll")                                                         \
        for (int i_ = 0; i_ < 4; ++i_)                                            \
            __builtin_amdgcn_global_load_lds(                                     \
                (const __attribute__((address_space(1))) void*)(Bsrc + (size_t)(i_ * 64) * K + (kt)), \
                (__attribute__((address_space(3))) void*)(&lds[b][16384 + tid * 8 + i_ * 4096]), 16, 0, 0);

    const int l15 = lane & 15, l7 = lane & 7, lhi = lane >> 4;
    const int xo0 = 8 * (lhi ^ l7);
    const int xo1 = 8 * ((lhi + 4) ^ l7);
    const int aRow = wrow * 128 + l15;
    const int bRow = wcol * 64 + l15;

    f32x4 acc[8][4];
    #pragma unroll
    for (int m = 0; m < 8; ++m)
        #pragma unroll
        for (int n = 0; n < 4; ++n) acc[m][n] = (f32x4){0.f, 0.f, 0.f, 0.f};

    STAGE_A(0, 0); STAGE_B(0, 0);
    STAGE_A(64, 1); STAGE_B(64, 1);
    asm volatile("s_waitcnt vmcnt(8)" ::: "memory");
    __builtin_amdgcn_s_barrier();

    for (int t = 0; t < NT; ++t) {
        const int cb = t & 1;
        const unsigned short* base = &lds[cb][0];
        const int ktp = (t + 2) << 6;
        const bool pf = (t + 2) < NT;

        short8 a[4][2], a2[4][2], bfr[4][2];
        // ---- pA: read a(mh0) + all b + a2(mh1); MFMA Q(0,*) x32 ----
        #pragma unroll
        for (int mf = 0; mf < 4; ++mf) {
            a[mf][0] = *(const short8*)(base + (aRow + mf * 16) * 64 + xo0);
            a[mf][1] = *(const short8*)(base + (aRow + mf * 16) * 64 + xo1);
        }
        #pragma unroll
        for (int nf = 0; nf < 4; ++nf) {
            bfr[nf][0] = *(const short8*)(base + 16384 + (bRow + nf * 16) * 64 + xo0);
            bfr[nf][1] = *(const short8*)(base + 16384 + (bRow + nf * 16) * 64 + xo1);
        }
        #pragma unroll
        for (int mf = 0; mf < 4; ++mf) {
            a2[mf][0] = *(const short8*)(base + (aRow + (mf + 4) * 16) * 64 + xo0);
            a2[mf][1] = *(const short8*)(base + (aRow + (mf + 4) * 16) * 64 + xo1);
        }
        __builtin_amdgcn_s_setprio(1);
        #pragma unroll
        for (int mf = 0; mf < 4; ++mf)
            #pragma unroll
            for (int nf = 0; nf < 4; ++nf)
                #pragma unroll
                for (int kk = 0; kk < 2; ++kk)
                    acc[mf][nf] = __builtin_amdgcn_mfma_f32_16x16x32_bf16(
                        a[mf][kk], bfr[nf][kk], acc[mf][nf], 0, 0, 0);
        __builtin_amdgcn_s_setprio(0);
        // a2 reads have no pre-barrier consumer: drain them explicitly so no
        // ds_read crosses bar1 into the region pB's stages overwrite.
        asm volatile("s_waitcnt lgkmcnt(0)" ::: "memory");
        __builtin_amdgcn_s_barrier();   // bar1: all LDS reads of buf[cb] done

        // ---- pB: stage B(t+2)+A(t+2); MFMA Q(1,*) x32 (reg-only) ----
        if (pf) { STAGE_B(ktp, cb); STAGE_A(ktp, cb); }
        __builtin_amdgcn_s_setprio(1);
        #pragma unroll
        for (int mf = 0; mf < 4; ++mf)
            #pragma unroll
            for (int nf = 0; nf < 4; ++nf)
                #pragma unroll
                for (int kk = 0; kk < 2; ++kk)
                    acc[4 + mf][nf] = __builtin_amdgcn_mfma_f32_16x16x32_bf16(
                        a2[mf][kk], bfr[nf][kk], acc[4 + mf][nf], 0, 0, 0);
        __builtin_amdgcn_s_setprio(0);

        // ---- tile boundary: counted wait for tile t+1; barrier ----
        if (t + 1 < NT) {
            if (pf) asm volatile("s_waitcnt vmcnt(8)" ::: "memory");
            else    asm volatile("s_waitcnt vmcnt(0)" ::: "memory");
            __builtin_amdgcn_s_barrier();   // bar2: tile t+1 data visible
        }
    }

    const int row0 = bm * 256 + wrow * 128 + lhi * 4;
    const int col0 = bn * 256 + wcol * 64 + l15;
    #pragma unroll
    for (int mf = 0; mf < 8; ++mf)
        #pragma unroll
        for (int nf = 0; nf < 4; ++nf)
            #pragma unroll
            for (int r = 0; r < 4; ++r)
                C[(size_t)(row0 + mf * 16 + r) * N + col0 + nf * 16] = f2bf(acc[mf][nf][r]);

    float s[4] = {0, 0, 0, 0}, sq[4] = {0, 0, 0, 0};
    #pragma unroll
    for (int mf = 0; mf < 8; ++mf)
        #pragma unroll
        for (int nf = 0; nf < 4; ++nf)
            #pragma unroll
            for (int r = 0; r < 4; ++r) {
                float v = acc[mf][nf][r];
                s[nf] += v; sq[nf] += v * v;
            }
    #pragma unroll
    for (int nf = 0; nf < 4; ++nf) {
        s[nf] += __shfl_xor(s[nf], 16); s[nf] += __shfl_xor(s[nf], 32);
        sq[nf] += __shfl_xor(sq[nf], 16); sq[nf] += __shfl_xor(sq[nf], 32);
    }
    if (lane < 16) {
        #pragma unroll
        for (int nf = 0; nf < 4; ++nf) {
            atomicAdd(&sums[col0 + nf * 16], s[nf]);
            atomicAdd(&sqs[col0 + nf * 16], sq[nf]);
        }
    }
    #undef STAGE_A
    #undef STAGE_B
}

// ---------------------------------------------------------------------------
// GEMM2 (exact R8 version, 142.7us config): BN1 coeffs per-block from raw
// stats; A = relu(BN1(z1)) reg-staged+transformed in flight; B double-buffered
// via global_load_lds with counted vmcnt(4); XOR swizzle; setprio; BN2 stats.
// 128x128 tile, 256 thr (~2 blocks/CU).
// ---------------------------------------------------------------------------
__global__ __launch_bounds__(256) void gemm2_fused(
    const unsigned short* __restrict__ z1,
    const unsigned short* __restrict__ Bt,
    unsigned short* __restrict__ C,
    const float* __restrict__ sums1, const float* __restrict__ sqs1,
    const float* __restrict__ g1, const float* __restrict__ be1,
    float* __restrict__ sums2, float* __restrict__ sqs2,
    int M, int N, int K, float invB)
{
    __shared__ unsigned short As[128 * 64];
    __shared__ unsigned short Bs[2][128 * 64];
    __shared__ float a1s[1024], b1s[1024];
    const int tid = threadIdx.x;
    const int lane = tid & 63;
    const int wave = tid >> 6;
    const int nbn = N >> 7;
    const int cpx = gridDim.x >> 3;
    const int swzb = (blockIdx.x & 7) * cpx + (blockIdx.x >> 3);
    const int bm = swzb / nbn, bn = swzb % nbn;
    const int NT = K >> 6;
    const int wr = (wave >> 1) << 6;
    const int wc = (wave & 1) << 6;

    for (int c = tid; c < K; c += 256) {
        float mu = sums1[c] * invB;
        float var = sqs1[c] * invB - mu * mu;
        float sc = g1[c] * rsqrtf(var + 1e-5f);
        a1s[c] = sc;
        b1s[c] = be1[c] - mu * sc;
    }
    __syncthreads();

    const int srow = tid >> 3;
    const int sca  = (tid & 7) ^ (srow & 7);
    const int acol = (tid & 7) * 8;
    const unsigned short* Asrc = z1 + (size_t)(bm * 128 + srow) * K + acol;
    const unsigned short* Bsrc = Bt + (size_t)(bn * 128 + srow) * K + sca * 8;

    #define STAGE_B2(kt, b)                                                     \
        _Pragma("unroll")                                                       \
        for (int i_ = 0; i_ < 4; ++i_)                                          \
            __builtin_amdgcn_global_load_lds(                                   \
                (const __attribute__((address_space(1))) void*)(Bsrc + (size_t)(i_ * 32) * K + (kt)), \
                (__attribute__((address_space(3))) void*)(&Bs[b][tid * 8 + i_ * 2048]), 16, 0, 0);

    const int l15 = lane & 15, l7 = lane & 7, lhi = lane >> 4;
    const int xo0 = 8 * (lhi ^ l7);
    const int xo1 = 8 * ((lhi + 4) ^ l7);

    f32x4 acc[4][4];
    #pragma unroll
    for (int m = 0; m < 4; ++m)
        #pragma unroll
        for (int n = 0; n < 4; ++n) acc[m][n] = (f32x4){0.f, 0.f, 0.f, 0.f};

    STAGE_B2(0, 0);
    u16x8 va[4];
    #pragma unroll
    for (int i = 0; i < 4; ++i)
        va[i] = *(const u16x8*)(Asrc + (size_t)(i * 32) * K);

    for (int t = 0; t < NT; ++t) {
        const int cur = t & 1;
        const int kt = t << 6;
        const bool pf = (t + 1) < NT;
        if (pf) { STAGE_B2(kt + 64, cur ^ 1); }
        if (pf) asm volatile("s_waitcnt vmcnt(4)" ::: "memory");
        else    asm volatile("s_waitcnt vmcnt(0)" ::: "memory");

        {
            const int c0 = kt + acol;
            float av[8], bv[8];
            #pragma unroll
            for (int jj = 0; jj < 8; ++jj) { av[jj] = a1s[c0 + jj]; bv[jj] = b1s[c0 + jj]; }
            #pragma unroll
            for (int i = 0; i < 4; ++i) {
                short8 w;
                #pragma unroll
                for (int jj = 0; jj < 8; ++jj)
                    w[jj] = (short)f2bf(fmaxf(av[jj] * bf2f(va[i][jj]) + bv[jj], 0.f));
                *(short8*)&As[(srow + i * 32) * 64 + 8 * sca] = w;
            }
        }
        if (pf) {
            #pragma unroll
            for (int i = 0; i < 4; ++i)
                va[i] = *(const u16x8*)(Asrc + (size_t)(i * 32) * K + kt + 64);
        }
        asm volatile("s_waitcnt lgkmcnt(0)" ::: "memory");
        __builtin_amdgcn_s_barrier();
        __builtin_amdgcn_sched_barrier(0);

        const unsigned short* bb = &Bs[cur][0];
        short8 af[4][2], bfv[4][2];
        #pragma unroll
        for (int m = 0; m < 4; ++m) {
            af[m][0] = *(const short8*)&As[(wr + m * 16 + l15) * 64 + xo0];
            af[m][1] = *(const short8*)&As[(wr + m * 16 + l15) * 64 + xo1];
        }
        #pragma unroll
        for (int n = 0; n < 4; ++n) {
            bfv[n][0] = *(const short8*)(bb + (wc + n * 16 + l15) * 64 + xo0);
            bfv[n][1] = *(const short8*)(bb + (wc + n * 16 + l15) * 64 + xo1);
        }
        __builtin_amdgcn_s_setprio(1);
        #pragma unroll
        for (int m = 0; m < 4; ++m)
            #pragma unroll
            for (int n = 0; n < 4; ++n)
                #pragma unroll
                for (int kk = 0; kk < 2; ++kk)
                    acc[m][n] = __builtin_amdgcn_mfma_f32_16x16x32_bf16(
                        af[m][kk], bfv[n][kk], acc[m][n], 0, 0, 0);
        __builtin_amdgcn_s_setprio(0);
        __builtin_amdgcn_s_barrier();
    }

    const int row0 = bm * 128 + wr + lhi * 4;
    const int col0 = bn * 128 + wc + l15;
    #pragma unroll
    for (int m = 0; m < 4; ++m)
        #pragma unroll
        for (int n = 0; n < 4; ++n)
            #pragma unroll
            for (int r = 0; r < 4; ++r)
                C[(size_t)(row0 + m * 16 + r) * N + col0 + n * 16] = f2bf(acc[m][n][r]);

    float s[4] = {0, 0, 0, 0}, q[4] = {0, 0, 0, 0};
    #pragma unroll
    for (int m = 0; m < 4; ++m)
        #pragma unroll
        for (int n = 0; n < 4; ++n)
            #pragma unroll
            for (int r = 0; r < 4; ++r) {
                float v = acc[m][n][r];
                s[n] += v; q[n] += v * v;
            }
    #pragma unroll
    for (int n = 0; n < 4; ++n) {
        s[n] += __shfl_xor(s[n], 16); s[n] += __shfl_xor(s[n], 32);
        q[n] += __shfl_xor(q[n], 16); q[n] += __shfl_xor(q[n], 32);
    }
    if (lane < 16) {
        #pragma unroll
        for (int n = 0; n < 4; ++n) {
            atomicAdd(&sums2[col0 + n * 16], s[n]);
            atomicAdd(&sqs2[col0 + n * 16], q[n]);
        }
    }
    #undef STAGE_B2
}

// ---------------------------------------------------------------------------
// Final: BN2 (coeffs from raw stats) + ReLU + dot(W3) + b3 + fm -> sigmoid
// ---------------------------------------------------------------------------
__global__ __launch_bounds__(256) void final_k(
    const unsigned short* __restrict__ z2,
    const float* __restrict__ sums2, const float* __restrict__ sqs2,
    const float* __restrict__ g2, const float* __restrict__ be2,
    const float* __restrict__ W3, const float* __restrict__ b3,
    const float* __restrict__ fm, float* __restrict__ out, float invB)
{
    int row = blockIdx.x * 4 + threadIdx.y;
    int lane = threadIdx.x;
    int c = lane * 8;
    u16x8 u = *(const u16x8*)&z2[(size_t)row * 512 + c];
    float dot = 0.f;
    #pragma unroll
    for (int j = 0; j < 8; ++j) {
        float mu = sums2[c + j] * invB;
        float var = sqs2[c + j] * invB - mu * mu;
        float a = g2[c + j] * rsqrtf(var + 1e-5f);
        float b = be2[c + j] - mu * a;
        float x = a * bf2f(u[j]) + b;
        dot += fmaxf(x, 0.f) * W3[c + j];
    }
    #pragma unroll
    for (int off = 32; off; off >>= 1) dot += __shfl_xor(dot, off);
    if (lane == 0) {
        float logit = fm[row] + dot + b3[0];
        float p = 1.f / (1.f + expf(-logit));
        out[row * 2 + 0] = 1.f - p;
        out[row * 2 + 1] = p;
    }
}

// ---------------------------------------------------------------------------
extern "C" void kernel_launch(void* const* d_in, const int* in_sizes, int n_in,
                              void* d_out, int out_size, void* d_ws, size_t ws_size,
                              hipStream_t stream)
{
    const int*   cat  = (const int*)d_in[0];
    const float* cont = (const float*)d_in[1];
    const float* bias = (const float*)d_in[2];
    const float* t1c  = (const float*)d_in[3];
    const float* t2c  = (const float*)d_in[4];
    const float* t1x  = (const float*)d_in[5];
    const float* t2x  = (const float*)d_in[6];
    const float* W1   = (const float*)d_in[7];
    // d_in[8] = b1: cancels under training-mode BN
    const float* g1   = (const float*)d_in[9];
    const float* be1  = (const float*)d_in[10];
    const float* W2   = (const float*)d_in[11];
    // d_in[12] = b2: cancels
    const float* g2   = (const float*)d_in[13];
    const float* be2  = (const float*)d_in[14];
    const float* W3   = (const float*)d_in[15];
    const float* b3   = (const float*)d_in[16];
    float* out = (float*)d_out;

    const int B = 16384, H1 = 1024, H2 = 512;

    uint8_t* p = (uint8_t*)d_ws;
    auto carve = [&](size_t bytes) {
        uint8_t* r = p;
        p += (bytes + 255) & ~(size_t)255;
        return r;
    };
    unsigned short* deep = (unsigned short*)carve((size_t)B * KP * 2);   // 56.6 MB
    unsigned short* w1t  = (unsigned short*)carve((size_t)H1 * KP * 2);
    unsigned short* w2t  = (unsigned short*)carve((size_t)H2 * H1 * 2);
    unsigned short* z1   = (unsigned short*)carve((size_t)B * H1 * 2);
    unsigned short* z2   = (unsigned short*)carve((size_t)B * H2 * 2);
    float* fm    = (float*)carve((size_t)B * 4);
    float* stats = (float*)carve((size_t)3072 * 4);
    float* sums1 = stats, *sqs1 = stats + H1, *sums2 = stats + 2 * H1, *sqs2 = stats + 2 * H1 + H2;

    // FRONT: embed+FM (4096) | W transposes (2176) | cont fold (52) | zero stats (1)
    front_k<<<NB_EMB + NB_TR + NB_FLD + 1, 256, 0, stream>>>(
        cat, cont, bias, t1c, t2c, t1x, t2x, deep, fm, W1, w1t, W2, w2t, stats);

    // GEMM1: K = 1728 (27 tiles), 2-barrier counted-vmcnt pipeline, fused BN1 stats
    gemm256<<<(B / 256) * (H1 / 256), 512, 0, stream>>>(deep, w1t, z1, sums1, sqs1, B, H1, KP);

    // GEMM2: 128x128 tiles (R8 config), BN1 coeff+apply+ReLU fused, BN2 stats
    gemm2_fused<<<(B / 128) * (H2 / 128), 256, 0, stream>>>(
        z1, w2t, z2, sums1, sqs1, g1, be1, sums2, sqs2, B, H2, H1, 1.f / B);

    final_k<<<B / 4, dim3(64, 4), 0, stream>>>(z2, sums2, sqs2, g2, be2, W3, b3, fm, out, 1.f / B);
}